// Round 11
// baseline (181.452 us; speedup 1.0000x reference)
//
#include <hip/hip_runtime.h>

#define HI 1440
#define WI 1920
#define NPIX (HI*WI)
#define EPSF 1e-8f

#define GCOLS 52            // valid output columns per wave
#define NG 37               // ceil(1920/52)
#define SROWS 22            // output rows per strip
#define NS 66               // ceil(1440/22)
#define NWAVES (NG*NS)      // 2442
#define PROWS 35            // raw iters per strip = SROWS+13 (delayed pipeline), mult of 7

typedef __fp16 h2 __attribute__((ext_vector_type(2)));

// ---------------- small 3x3 helpers ----------------
__device__ __forceinline__ void mat3mul(const float* A, const float* B, float* C) {
#pragma unroll
  for (int i = 0; i < 3; ++i)
#pragma unroll
    for (int j = 0; j < 3; ++j)
      C[i*3+j] = A[i*3+0]*B[0+j] + A[i*3+1]*B[3+j] + A[i*3+2]*B[6+j];
}

__device__ void rodrigues_dev(const float* v, float* R) {
  float th = sqrtf(v[0]*v[0] + v[1]*v[1] + v[2]*v[2]) + 1e-12f;
  float kx = v[0]/th, ky = v[1]/th, kz = v[2]/th;
  float st = sinf(th), ct = cosf(th);
  float S[9] = {0.f,-kz,ky, kz,0.f,-kx, -ky,kx,0.f};
  float S2[9];
  mat3mul(S, S, S2);
#pragma unroll
  for (int i = 0; i < 9; ++i) R[i] = st*S[i] + (1.f-ct)*S2[i];
  R[0] += 1.f; R[4] += 1.f; R[8] += 1.f;
}

// Shared by k_pre (fallback path) and k_warp's per-block prologue.
// M[0..11]=target0, M[12..23]=target1, M[24]=f. Pure fp32, deterministic.
__device__ void compute_mats(float f, const float* __restrict__ aa,
                             const float* __restrict__ cen, float* M) {
  const float u0 = WI*0.5f - 0.5f;
  const float v0 = HI*0.5f - 0.5f;
  float K[9]  = {f,0.f,u0, 0.f,f,v0, 0.f,0.f,1.f};
  float Ki[9] = {1.f/f,0.f,-u0/f, 0.f,1.f/f,-v0/f, 0.f,0.f,1.f};
  float R1[9]; rodrigues_dev(aa, R1);
  float R1T[9];
  for (int i = 0; i < 3; ++i)
    for (int j = 0; j < 3; ++j) R1T[i*3+j] = R1[j*3+i];
  for (int t = 0; t < 2; ++t) {
    float Rt[9]; rodrigues_dev(aa + 3*(t+1), Rt);
    float A[9]; mat3mul(K, Rt, A);
    float Tm[9]; mat3mul(A, R1T, Tm);
    float B[9]; mat3mul(Tm, Ki, B);
    float Cd[3] = {cen[0]-cen[3*(t+1)+0], cen[1]-cen[3*(t+1)+1], cen[2]-cen[3*(t+1)+2]};
    float a0 = A[0]*Cd[0]+A[1]*Cd[1]+A[2]*Cd[2];
    float a1 = A[3]*Cd[0]+A[4]*Cd[1]+A[5]*Cd[2];
    float a2 = A[6]*Cd[0]+A[7]*Cd[1]+A[8]*Cd[2];
    float* Mo = M + t*12;
    for (int i = 0; i < 9; ++i) Mo[i] = B[i];
    Mo[9] = a0; Mo[10] = a1; Mo[11] = a2;
  }
  M[24] = f;
}

__global__ void k_pre(const float* __restrict__ focal, const float* __restrict__ aa,
                      const float* __restrict__ cen, float* __restrict__ mats) {
  if (threadIdx.x != 0 || blockIdx.x != 0) return;
  compute_mats(focal[0], aa, cen, mats);
}

// bilerp with int-domain clamped addressing (validity bools zero the value).
__device__ __forceinline__ float bilerp(const float* __restrict__ img, float px, float py) {
  float x0 = floorf(px), y0 = floorf(py);
  float wx = px - x0, wy = py - y0;
  bool bx0 = (x0 >= 0.f)  && (x0 <= (float)(WI-1));
  bool bx1 = (x0 >= -1.f) && (x0 <= (float)(WI-2));
  bool by0 = (y0 >= 0.f)  && (y0 <= (float)(HI-1));
  bool by1 = (y0 >= -1.f) && (y0 <= (float)(HI-2));
  int ix = (int)x0, iy = (int)y0;
  int ix0 = min(max(ix, 0), WI-1);
  int ix1 = min(max(ix+1, 0), WI-1);
  int iy0 = min(max(iy, 0), HI-1);
  int iy1 = min(max(iy+1, 0), HI-1);
  const float* r0 = img + iy0*WI;
  const float* r1 = img + iy1*WI;
  float v00 = (bx0&&by0) ? r0[ix0] : 0.f;
  float v10 = (bx1&&by0) ? r0[ix1] : 0.f;
  float v01 = (bx0&&by1) ? r1[ix0] : 0.f;
  float v11 = (bx1&&by1) ? r1[ix1] : 0.f;
  return (1.f-wy)*((1.f-wx)*v00 + wx*v10) + wy*((1.f-wx)*v01 + wx*v11);
}

// 7-tap centered horizontal sum on packed fp16 pairs, 5 shuffles (tree).
__device__ __forceinline__ h2 hsum7p(h2 v, int ln) {
  int vi = __builtin_bit_cast(int, v);
  h2 a = __builtin_bit_cast(h2, __shfl(vi, ln-3, 64));   // v[i-3]
  h2 b = __builtin_bit_cast(h2, __shfl(vi, ln-2, 64));   // v[i-2]
  h2 p1 = a + b;
  int p1i = __builtin_bit_cast(int, p1);
  h2 c = __builtin_bit_cast(h2, __shfl(p1i, ln+2, 64));  // v[i-1]+v[i]
  h2 d = __builtin_bit_cast(h2, __shfl(p1i, ln+4, 64));  // v[i+1]+v[i+2]
  h2 e = __builtin_bit_cast(h2, __shfl(vi, ln+3, 64));   // v[i+3]
  return (p1 + c) + (d + e);
}

__device__ __forceinline__ float loadI(const float* __restrict__ p, int x, int y) {
  return (x >= 0 && x < WI && y >= 0 && y < HI) ? p[y*WI + x] : 0.f;
}

// ============ PASS 1: per-pixel warp+gather (R6 form + inlined mats) ========
// Thread 0 computes the homography matrices into LDS (identical fp32 code ->
// bit-identical across blocks); removes the k_pre dispatch from the hot path.
__global__ __launch_bounds__(256) void k_warp(const float* __restrict__ depth,
                                              const float* __restrict__ tgts,
                                              const float* __restrict__ focal,
                                              const float* __restrict__ aa,
                                              const float* __restrict__ cen,
                                              unsigned* __restrict__ wmap) {
  __shared__ float Msh[25];
  if (threadIdx.x == 0) compute_mats(focal[0], aa, cen, Msh);
  __syncthreads();

  const int idx = blockIdx.x*256 + threadIdx.x;   // NPIX % 256 == 0, no tail
  const int y = idx / WI;
  const int x = idx - y*WI;

  const float f = Msh[24];
  float M0[12], M1[12];
#pragma unroll
  for (int i = 0; i < 12; ++i) { M0[i] = Msh[i]; M1[i] = Msh[12+i]; }

  const float fx = (float)x, fy = (float)y;
  const float finv = 1.f/f;
  const float pxc = (fx - 959.5f)*finv;

  float d   = depth[idx];
  float dm  = (x > 0)     ? depth[idx-1]  : 0.f;
  float dp  = (x < WI-1)  ? depth[idx+1]  : 0.f;
  float dvm = (y > 0)     ? depth[idx-WI] : 0.f;
  float dvp = (y < HI-1)  ? depth[idx+WI] : 0.f;
  float du = 0.5f*(dp - dm);
  float dv = 0.5f*(dvp - dvm);
  float nx = f*du, ny = f*dv;
  float nz = (960.f - fx)*du + (720.f - fy)*dv - d;
  float nn = sqrtf(nx*nx + ny*ny + nz*nz) + EPSF;
  float wsc = __builtin_amdgcn_rcpf(nn*(d + EPSF));
  float pyc = (fy - 719.5f)*finv;
  float sv = (nx*pxc + ny*pyc + nz)*wsc;

  float w0, w1;
  {
    const float LA0 = M0[0]*fx + M0[2];
    const float LA1 = M0[3]*fx + M0[5];
    const float LA2 = M0[6]*fx + M0[8];
    float a0 = fmaf(M0[9],  sv, fmaf(M0[1], fy, LA0));
    float a1 = fmaf(M0[10], sv, fmaf(M0[4], fy, LA1));
    float a2 = fmaf(M0[11], sv, fmaf(M0[7], fy, LA2));
    float iz = __builtin_amdgcn_rcpf(a2 + EPSF);
    w0 = bilerp(tgts, a0*iz, a1*iz);
  }
  {
    const float LB0 = M1[0]*fx + M1[2];
    const float LB1 = M1[3]*fx + M1[5];
    const float LB2 = M1[6]*fx + M1[8];
    float a0 = fmaf(M1[9],  sv, fmaf(M1[1], fy, LB0));
    float a1 = fmaf(M1[10], sv, fmaf(M1[4], fy, LB1));
    float a2 = fmaf(M1[11], sv, fmaf(M1[7], fy, LB2));
    float iz = __builtin_amdgcn_rcpf(a2 + EPSF);
    w1 = bilerp(tgts + NPIX, a0*iz, a1*iz);
  }
  wmap[idx] = __builtin_bit_cast(unsigned, __builtin_amdgcn_cvt_pkrtz(w0, w1));
}

// ============ PASS 2: windowed ZNCC from (ref, wmap) — R6 guarded form =====
__global__ __launch_bounds__(256) void k_win(const float* __restrict__ ref,
                                             const unsigned* __restrict__ wmap,
                                             float* __restrict__ partials) {
  const int wid = blockIdx.x*4 + (threadIdx.x >> 6);
  if (wid >= NWAVES) return;
  const int ln = threadIdx.x & 63;
  const int g = wid % NG, st = wid / NG;
  const int R0 = st * SROWS;
  const int x = g*GCOLS - 6 + ln;
  const bool xok = (x >= 0) && (x < WI);

  float rring[7];
  h2 wring[7];
  float Hr[7], H0[7], H1[7];
  float Qrr[7], Qrt0[7], Qtt0[7], Qrt1[7], Qtt1[7];
  const h2 hz = {(__fp16)0.f, (__fp16)0.f};
#pragma unroll
  for (int k = 0; k < 7; ++k) {
    rring[k]=0.f; wring[k]=hz;
    Hr[k]=0.f; H0[k]=0.f; H1[k]=0.f;
    Qrr[k]=0.f; Qrt0[k]=0.f; Qtt0[k]=0.f; Qrt1[k]=0.f; Qtt1[k]=0.f;
  }
  float Sr=0.f, S0=0.f, S1=0.f;
  float Vrr=0.f, Vrt0=0.f, Vtt0=0.f, Vrt1=0.f, Vtt1=0.f;
  float cr_p=0.f, c0_p=0.f, c1_p=0.f;   // centered values for row y-4 (prev iter)
  float acc_s=0.f, acc_c=0.f;

  for (int ib = 0; ib < PROWS; ib += 7) {
#pragma unroll
    for (int j = 0; j < 7; ++j) {
      const int y = R0 - 6 + ib + j;
      // raw warped mask for row yo = y-7: capture before overwriting slot j
      const int mb = __builtin_bit_cast(int, wring[j]);

      // ---- static-address inputs at (x,y) ----
      float r = 0.f;
      h2 wp = hz;
      if (xok && y >= 0 && y < HI) {
        const int gidx = y*WI + x;
        r  = ref[gidx];
        wp = __builtin_bit_cast(h2, wmap[gidx]);
      }
      rring[j] = r;
      wring[j] = wp;

      // ---- 4 packed horizontal 7-sums (20 bpermutes total) ----
      h2 A = hsum7p(__builtin_amdgcn_cvt_pkrtz(r, cr_p*cr_p), ln);
      h2 B = hsum7p(wp, ln);
      h2 C = hsum7p(__builtin_amdgcn_cvt_pkrtz(cr_p*c0_p, c0_p*c0_p), ln);
      h2 D = hsum7p(__builtin_amdgcn_cvt_pkrtz(cr_p*c1_p, c1_p*c1_p), ln);
      float hr   = (float)A.x, prr  = (float)A.y;
      float h0   = (float)B.x, h1   = (float)B.y;
      float hrt0 = (float)C.x, htt0 = (float)C.y;
      float hrt1 = (float)D.x, htt1 = (float)D.y;

      // ---- raw vertical box sums; box complete at yc = y-3 ----
      Sr += hr; S0 += h0; S1 += h1;
      const float Br = Sr, B0 = S0, B1 = S1;
      Sr -= Hr[(j+1)%7]; S0 -= H0[(j+1)%7]; S1 -= H1[(j+1)%7];
      Hr[j] = hr; H0[j] = h0; H1[j] = h1;

      // ---- new centered values for row yc = y-3 (consumed NEXT iteration) ----
      const int yc = y - 3;
      float crn = 0.f, c0n = 0.f, c1n = 0.f;
      if (xok && yc >= 0 && yc < HI) {
        h2 wc = wring[(j+4)%7];
        crn = rring[(j+4)%7] - Br*(1.f/49.f);
        c0n = (float)wc.x - B0*(1.f/49.f);
        c1n = (float)wc.y - B1*(1.f/49.f);
      }

      // ---- product vertical sums: this iteration adds product row y-4 ----
      Vrr += prr; Vrt0 += hrt0; Vtt0 += htt0; Vrt1 += hrt1; Vtt1 += htt1;

      // window complete for output row yo = y-7
      const int yo = y - 7;
      if (yo >= R0 && yo < R0 + SROWS && yo < HI && ln >= 6 && ln <= 57 && x < WI) {
        const float inv49 = 1.f/49.f;
        float vr = Vrr*inv49;
        if (mb & 0xffff) {
          float zm = (Vrt0*inv49) * __builtin_amdgcn_rsqf(vr*(Vtt0*inv49) + EPSF);
          acc_s += zm; acc_c += 1.f;
        }
        if (((unsigned)mb >> 16) != 0u) {
          float zm = (Vrt1*inv49) * __builtin_amdgcn_rsqf(vr*(Vtt1*inv49) + EPSF);
          acc_s += zm; acc_c += 1.f;
        }
      }

      Vrr -= Qrr[(j+5)%7]; Vrt0 -= Qrt0[(j+5)%7]; Vtt0 -= Qtt0[(j+5)%7];
      Vrt1 -= Qrt1[(j+5)%7]; Vtt1 -= Qtt1[(j+5)%7];
      Qrr[(j+4)%7] = prr; Qrt0[(j+4)%7] = hrt0; Qtt0[(j+4)%7] = htt0;
      Qrt1[(j+4)%7] = hrt1; Qtt1[(j+4)%7] = htt1;

      cr_p = crn; c0_p = c0n; c1_p = c1n;
    }
  }

  // ---- wave reduce, one partial pair per wave ----
#pragma unroll
  for (int off = 32; off > 0; off >>= 1) {
    acc_s += __shfl_down(acc_s, off, 64);
    acc_c += __shfl_down(acc_c, off, 64);
  }
  if (ln == 0) { partials[2*wid] = acc_s; partials[2*wid+1] = acc_c; }
}

// ============ fallback: fused kernel (used if workspace too small) ======
__global__ __launch_bounds__(256) void k_stream(const float* __restrict__ depth,
                                                const float* __restrict__ ref,
                                                const float* __restrict__ tgts,
                                                const float* __restrict__ mats,
                                                float* __restrict__ partials) {
  const int wid = blockIdx.x*4 + (threadIdx.x >> 6);
  if (wid >= NWAVES) return;
  const int ln = threadIdx.x & 63;
  const int g = wid % NG, st = wid / NG;
  const int R0 = st * SROWS;
  const int x = g*GCOLS - 6 + ln;
  const bool xok = (x >= 0) && (x < WI);

  const float f = mats[24];
  float M0[12], M1[12];
#pragma unroll
  for (int i = 0; i < 12; ++i) { M0[i] = mats[i]; M1[i] = mats[12+i]; }

  const float fx = (float)x;
  const float finv = 1.f/f;
  const float pxc = (fx - 959.5f)*finv;
  const float LA0 = M0[0]*fx + M0[2];
  const float LA1 = M0[3]*fx + M0[5];
  const float LA2 = M0[6]*fx + M0[8];
  const float LB0 = M1[0]*fx + M1[2];
  const float LB1 = M1[3]*fx + M1[5];
  const float LB2 = M1[6]*fx + M1[8];

  float dring[7], rring[7];
  h2 wring[7];
  float Hr[7], H0[7], H1[7];
  float Qrr[7], Qrt0[7], Qtt0[7], Qrt1[7], Qtt1[7];
  const h2 hz = {(__fp16)0.f, (__fp16)0.f};
#pragma unroll
  for (int k = 0; k < 7; ++k) {
    dring[k]=0.f; rring[k]=0.f; wring[k]=hz;
    Hr[k]=0.f; H0[k]=0.f; H1[k]=0.f;
    Qrr[k]=0.f; Qrt0[k]=0.f; Qtt0[k]=0.f; Qrt1[k]=0.f; Qtt1[k]=0.f;
  }
  float Sr=0.f, S0=0.f, S1=0.f;
  float Vrr=0.f, Vrt0=0.f, Vtt0=0.f, Vrt1=0.f, Vtt1=0.f;
  float cr_p=0.f, c0_p=0.f, c1_p=0.f;
  float acc_s=0.f, acc_c=0.f;

  dring[6] = loadI(depth, x, R0-7);
  dring[0] = loadI(depth, x, R0-6);

  for (int ib = 0; ib < PROWS; ib += 7) {
#pragma unroll
    for (int j = 0; j < 7; ++j) {
      const int y = R0 - 6 + ib + j;
      const int mb = __builtin_bit_cast(int, wring[j]);

      dring[(j+1)%7] = loadI(depth, x, y+1);

      float r = 0.f, w0 = 0.f, w1 = 0.f;
      if (xok && y >= 0 && y < HI) {
        const int gidx = y*WI + x;
        r = ref[gidx];
        float d  = dring[j];
        float dm = (x > 0)    ? depth[gidx-1] : 0.f;
        float dp = (x < WI-1) ? depth[gidx+1] : 0.f;
        float du = 0.5f*(dp - dm);
        float dv = 0.5f*(dring[(j+1)%7] - dring[(j+6)%7]);
        const float fy = (float)y;
        float nx = f*du, ny = f*dv;
        float nz = (960.f - fx)*du + (720.f - fy)*dv - d;
        float nn = sqrtf(nx*nx + ny*ny + nz*nz) + EPSF;
        float wsc = __builtin_amdgcn_rcpf(nn*(d + EPSF));
        float pyc = (fy - 719.5f)*finv;
        float sv = (nx*pxc + ny*pyc + nz)*wsc;
        {
          float a0 = fmaf(M0[9],  sv, fmaf(M0[1], fy, LA0));
          float a1 = fmaf(M0[10], sv, fmaf(M0[4], fy, LA1));
          float a2 = fmaf(M0[11], sv, fmaf(M0[7], fy, LA2));
          float iz = __builtin_amdgcn_rcpf(a2 + EPSF);
          w0 = bilerp(tgts, a0*iz, a1*iz);
        }
        {
          float a0 = fmaf(M1[9],  sv, fmaf(M1[1], fy, LB0));
          float a1 = fmaf(M1[10], sv, fmaf(M1[4], fy, LB1));
          float a2 = fmaf(M1[11], sv, fmaf(M1[7], fy, LB2));
          float iz = __builtin_amdgcn_rcpf(a2 + EPSF);
          w1 = bilerp(tgts + NPIX, a0*iz, a1*iz);
        }
      }
      rring[j] = r;
      h2 wp = __builtin_amdgcn_cvt_pkrtz(w0, w1);
      wring[j] = wp;

      h2 A = hsum7p(__builtin_amdgcn_cvt_pkrtz(r, cr_p*cr_p), ln);
      h2 B = hsum7p(wp, ln);
      h2 C = hsum7p(__builtin_amdgcn_cvt_pkrtz(cr_p*c0_p, c0_p*c0_p), ln);
      h2 D = hsum7p(__builtin_amdgcn_cvt_pkrtz(cr_p*c1_p, c1_p*c1_p), ln);
      float hr   = (float)A.x, prr  = (float)A.y;
      float h0   = (float)B.x, h1   = (float)B.y;
      float hrt0 = (float)C.x, htt0 = (float)C.y;
      float hrt1 = (float)D.x, htt1 = (float)D.y;

      Sr += hr; S0 += h0; S1 += h1;
      const float Br = Sr, B0 = S0, B1 = S1;
      Sr -= Hr[(j+1)%7]; S0 -= H0[(j+1)%7]; S1 -= H1[(j+1)%7];
      Hr[j] = hr; H0[j] = h0; H1[j] = h1;

      const int yc = y - 3;
      float crn = 0.f, c0n = 0.f, c1n = 0.f;
      if (xok && yc >= 0 && yc < HI) {
        h2 wc = wring[(j+4)%7];
        crn = rring[(j+4)%7] - Br*(1.f/49.f);
        c0n = (float)wc.x - B0*(1.f/49.f);
        c1n = (float)wc.y - B1*(1.f/49.f);
      }

      Vrr += prr; Vrt0 += hrt0; Vtt0 += htt0; Vrt1 += hrt1; Vtt1 += htt1;

      const int yo = y - 7;
      if (yo >= R0 && yo < R0 + SROWS && yo < HI && ln >= 6 && ln <= 57 && x < WI) {
        const float inv49 = 1.f/49.f;
        float vr = Vrr*inv49;
        if (mb & 0xffff) {
          float zm = (Vrt0*inv49) * __builtin_amdgcn_rsqf(vr*(Vtt0*inv49) + EPSF);
          acc_s += zm; acc_c += 1.f;
        }
        if (((unsigned)mb >> 16) != 0u) {
          float zm = (Vrt1*inv49) * __builtin_amdgcn_rsqf(vr*(Vtt1*inv49) + EPSF);
          acc_s += zm; acc_c += 1.f;
        }
      }

      Vrr -= Qrr[(j+5)%7]; Vrt0 -= Qrt0[(j+5)%7]; Vtt0 -= Qtt0[(j+5)%7];
      Vrt1 -= Qrt1[(j+5)%7]; Vtt1 -= Qtt1[(j+5)%7];
      Qrr[(j+4)%7] = prr; Qrt0[(j+4)%7] = hrt0; Qtt0[(j+4)%7] = htt0;
      Qrt1[(j+4)%7] = hrt1; Qtt1[(j+4)%7] = htt1;

      cr_p = crn; c0_p = c0n; c1_p = c1n;
    }
  }

#pragma unroll
  for (int off = 32; off > 0; off >>= 1) {
    acc_s += __shfl_down(acc_s, off, 64);
    acc_c += __shfl_down(acc_c, off, 64);
  }
  if (ln == 0) { partials[2*wid] = acc_s; partials[2*wid+1] = acc_c; }
}

__global__ __launch_bounds__(256) void k_final(const float* __restrict__ partials, int nb,
                                               float* __restrict__ out) {
  float s = 0.f, c = 0.f;
  for (int i = threadIdx.x; i < nb; i += 256) {
    s += partials[2*i];
    c += partials[2*i+1];
  }
#pragma unroll
  for (int off = 32; off > 0; off >>= 1) {
    s += __shfl_down(s, off, 64);
    c += __shfl_down(c, off, 64);
  }
  __shared__ float red[8];
  int tid = threadIdx.x;
  if ((tid & 63) == 0) { red[(tid>>6)*2] = s; red[(tid>>6)*2+1] = c; }
  __syncthreads();
  if (tid == 0) {
    float S = red[0]+red[2]+red[4]+red[6];
    float C = red[1]+red[3]+red[5]+red[7];
    float mean = S / fmaxf(C, 1.f);
    out[0] = (C > 0.f) ? 0.5f*(1.f - mean) : 0.f;
  }
}

extern "C" void kernel_launch(void* const* d_in, const int* in_sizes, int n_in,
                              void* d_out, int out_size, void* d_ws, size_t ws_size,
                              hipStream_t stream) {
  const float* focal  = (const float*)d_in[0];
  const float* aa     = (const float*)d_in[1];
  const float* cen    = (const float*)d_in[2];
  const float* ref    = (const float*)d_in[3];
  const float* depth  = (const float*)d_in[4];
  const float* tgts   = (const float*)d_in[5];
  float* out = (float*)d_out;

  float* wsf      = (float*)d_ws;
  float* mats     = wsf;                       // 32 floats (fallback path only)
  float* partials = wsf + 32;                  // 2*NWAVES floats
  unsigned* wmap  = (unsigned*)(wsf + 32 + 2*NWAVES);   // NPIX u32

  const size_t need = (size_t)(32 + 2*NWAVES)*4 + (size_t)NPIX*4;

  if (ws_size >= need) {
    k_warp<<<NPIX/256, 256, 0, stream>>>(depth, tgts, focal, aa, cen, wmap);
    k_win<<<(NWAVES + 3)/4, 256, 0, stream>>>(ref, wmap, partials);
  } else {
    k_pre<<<1, 64, 0, stream>>>(focal, aa, cen, mats);
    k_stream<<<(NWAVES + 3)/4, 256, 0, stream>>>(depth, ref, tgts, mats, partials);
  }
  k_final<<<1, 256, 0, stream>>>(partials, NWAVES, out);
}

// Round 12
// 145.843 us; speedup vs baseline: 1.2442x; 1.2442x over previous
//
#include <hip/hip_runtime.h>

#define HI 1440
#define WI 1920
#define NPIX (HI*WI)
#define EPSF 1e-8f

#define GCOLS 52            // valid output columns per wave
#define NG 37               // ceil(1920/52)
#define SROWS 22            // output rows per strip
#define NS 66               // ceil(1440/22)
#define NWAVES (NG*NS)      // 2442
#define PROWS 35            // raw iters per strip = SROWS+13 (delayed pipeline), mult of 7

typedef __fp16 h2 __attribute__((ext_vector_type(2)));

// ---------------- small 3x3 helpers (k_pre only) ----------------
__device__ __forceinline__ void mat3mul(const float* A, const float* B, float* C) {
#pragma unroll
  for (int i = 0; i < 3; ++i)
#pragma unroll
    for (int j = 0; j < 3; ++j)
      C[i*3+j] = A[i*3+0]*B[0+j] + A[i*3+1]*B[3+j] + A[i*3+2]*B[6+j];
}

__device__ void rodrigues_dev(const float* v, float* R) {
  float th = sqrtf(v[0]*v[0] + v[1]*v[1] + v[2]*v[2]) + 1e-12f;
  float kx = v[0]/th, ky = v[1]/th, kz = v[2]/th;
  float st = sinf(th), ct = cosf(th);
  float S[9] = {0.f,-kz,ky, kz,0.f,-kx, -ky,kx,0.f};
  float S2[9];
  mat3mul(S, S, S2);
#pragma unroll
  for (int i = 0; i < 9; ++i) R[i] = st*S[i] + (1.f-ct)*S2[i];
  R[0] += 1.f; R[4] += 1.f; R[8] += 1.f;
}

__global__ void k_pre(const float* __restrict__ focal, const float* __restrict__ aa,
                      const float* __restrict__ cen, float* __restrict__ mats) {
  if (threadIdx.x != 0 || blockIdx.x != 0) return;
  float f = focal[0];
  const float u0 = WI*0.5f - 0.5f;
  const float v0 = HI*0.5f - 0.5f;
  float K[9]  = {f,0.f,u0, 0.f,f,v0, 0.f,0.f,1.f};
  float Ki[9] = {1.f/f,0.f,-u0/f, 0.f,1.f/f,-v0/f, 0.f,0.f,1.f};
  float R1[9]; rodrigues_dev(aa, R1);
  float R1T[9];
  for (int i = 0; i < 3; ++i)
    for (int j = 0; j < 3; ++j) R1T[i*3+j] = R1[j*3+i];
  for (int t = 0; t < 2; ++t) {
    float Rt[9]; rodrigues_dev(aa + 3*(t+1), Rt);
    float A[9]; mat3mul(K, Rt, A);
    float Tm[9]; mat3mul(A, R1T, Tm);
    float B[9]; mat3mul(Tm, Ki, B);
    float Cd[3] = {cen[0]-cen[3*(t+1)+0], cen[1]-cen[3*(t+1)+1], cen[2]-cen[3*(t+1)+2]};
    float a0 = A[0]*Cd[0]+A[1]*Cd[1]+A[2]*Cd[2];
    float a1 = A[3]*Cd[0]+A[4]*Cd[1]+A[5]*Cd[2];
    float a2 = A[6]*Cd[0]+A[7]*Cd[1]+A[8]*Cd[2];
    float* M = mats + t*12;
    for (int i = 0; i < 9; ++i) M[i] = B[i];
    M[9] = a0; M[10] = a1; M[11] = a2;
  }
  mats[24] = f;
}

// bilerp with int-domain clamped addressing (validity bools zero the value).
__device__ __forceinline__ float bilerp(const float* __restrict__ img, float px, float py) {
  float x0 = floorf(px), y0 = floorf(py);
  float wx = px - x0, wy = py - y0;
  bool bx0 = (x0 >= 0.f)  && (x0 <= (float)(WI-1));
  bool bx1 = (x0 >= -1.f) && (x0 <= (float)(WI-2));
  bool by0 = (y0 >= 0.f)  && (y0 <= (float)(HI-1));
  bool by1 = (y0 >= -1.f) && (y0 <= (float)(HI-2));
  int ix = (int)x0, iy = (int)y0;
  int ix0 = min(max(ix, 0), WI-1);
  int ix1 = min(max(ix+1, 0), WI-1);
  int iy0 = min(max(iy, 0), HI-1);
  int iy1 = min(max(iy+1, 0), HI-1);
  const float* r0 = img + iy0*WI;
  const float* r1 = img + iy1*WI;
  float v00 = (bx0&&by0) ? r0[ix0] : 0.f;
  float v10 = (bx1&&by0) ? r0[ix1] : 0.f;
  float v01 = (bx0&&by1) ? r1[ix0] : 0.f;
  float v11 = (bx1&&by1) ? r1[ix1] : 0.f;
  return (1.f-wy)*((1.f-wx)*v00 + wx*v10) + wy*((1.f-wx)*v01 + wx*v11);
}

// 7-tap centered horizontal sum on packed fp16 pairs, 5 shuffles (tree).
__device__ __forceinline__ h2 hsum7p(h2 v, int ln) {
  int vi = __builtin_bit_cast(int, v);
  h2 a = __builtin_bit_cast(h2, __shfl(vi, ln-3, 64));   // v[i-3]
  h2 b = __builtin_bit_cast(h2, __shfl(vi, ln-2, 64));   // v[i-2]
  h2 p1 = a + b;
  int p1i = __builtin_bit_cast(int, p1);
  h2 c = __builtin_bit_cast(h2, __shfl(p1i, ln+2, 64));  // v[i-1]+v[i]
  h2 d = __builtin_bit_cast(h2, __shfl(p1i, ln+4, 64));  // v[i+1]+v[i+2]
  h2 e = __builtin_bit_cast(h2, __shfl(vi, ln+3, 64));   // v[i+3]
  return (p1 + c) + (d + e);
}

__device__ __forceinline__ float loadI(const float* __restrict__ p, int x, int y) {
  return (x >= 0 && x < WI && y >= 0 && y < HI) ? p[y*WI + x] : 0.f;
}

// ============ PASS 1: per-pixel warp+gather, no windows, no halo ============
// Each thread computes one pixel's (w0,w1), packed fp16, stored to wmap.
// Bound by unique-cacheline throughput of the scattered taps (4 lines/pixel,
// random depth -> no coalescing); instruction/latency restructures are
// neutral (R8-R10), so keep the simplest form.
__global__ __launch_bounds__(256) void k_warp(const float* __restrict__ depth,
                                              const float* __restrict__ tgts,
                                              const float* __restrict__ mats,
                                              unsigned* __restrict__ wmap) {
  const int idx = blockIdx.x*256 + threadIdx.x;
  if (idx >= NPIX) return;
  const int y = idx / WI;
  const int x = idx - y*WI;

  const float f = mats[24];
  float M0[12], M1[12];
#pragma unroll
  for (int i = 0; i < 12; ++i) { M0[i] = mats[i]; M1[i] = mats[12+i]; }

  const float fx = (float)x, fy = (float)y;
  const float finv = 1.f/f;
  const float pxc = (fx - 959.5f)*finv;

  float d   = depth[idx];
  float dm  = (x > 0)     ? depth[idx-1]  : 0.f;
  float dp  = (x < WI-1)  ? depth[idx+1]  : 0.f;
  float dvm = (y > 0)     ? depth[idx-WI] : 0.f;
  float dvp = (y < HI-1)  ? depth[idx+WI] : 0.f;
  float du = 0.5f*(dp - dm);
  float dv = 0.5f*(dvp - dvm);
  float nx = f*du, ny = f*dv;
  float nz = (960.f - fx)*du + (720.f - fy)*dv - d;
  float nn = sqrtf(nx*nx + ny*ny + nz*nz) + EPSF;
  float wsc = __builtin_amdgcn_rcpf(nn*(d + EPSF));
  float pyc = (fy - 719.5f)*finv;
  float sv = (nx*pxc + ny*pyc + nz)*wsc;

  float w0, w1;
  {
    const float LA0 = M0[0]*fx + M0[2];
    const float LA1 = M0[3]*fx + M0[5];
    const float LA2 = M0[6]*fx + M0[8];
    float a0 = fmaf(M0[9],  sv, fmaf(M0[1], fy, LA0));
    float a1 = fmaf(M0[10], sv, fmaf(M0[4], fy, LA1));
    float a2 = fmaf(M0[11], sv, fmaf(M0[7], fy, LA2));
    float iz = __builtin_amdgcn_rcpf(a2 + EPSF);
    w0 = bilerp(tgts, a0*iz, a1*iz);
  }
  {
    const float LB0 = M1[0]*fx + M1[2];
    const float LB1 = M1[3]*fx + M1[5];
    const float LB2 = M1[6]*fx + M1[8];
    float a0 = fmaf(M1[9],  sv, fmaf(M1[1], fy, LB0));
    float a1 = fmaf(M1[10], sv, fmaf(M1[4], fy, LB1));
    float a2 = fmaf(M1[11], sv, fmaf(M1[7], fy, LB2));
    float iz = __builtin_amdgcn_rcpf(a2 + EPSF);
    w1 = bilerp(tgts + NPIX, a0*iz, a1*iz);
  }
  wmap[idx] = __builtin_bit_cast(unsigned, __builtin_amdgcn_cvt_pkrtz(w0, w1));
}

// ============ PASS 2: windowed ZNCC from (ref, wmap) ============
// Same machinery as the fused kernel, but inputs are 2 static coalesced
// loads per row. Guarded-load form (best measured; unconditional-clamp and
// prefetch-ring variants were neutral-to-worse, R8/R9).
__global__ __launch_bounds__(256) void k_win(const float* __restrict__ ref,
                                             const unsigned* __restrict__ wmap,
                                             float* __restrict__ partials) {
  const int wid = blockIdx.x*4 + (threadIdx.x >> 6);
  if (wid >= NWAVES) return;
  const int ln = threadIdx.x & 63;
  const int g = wid % NG, st = wid / NG;
  const int R0 = st * SROWS;
  const int x = g*GCOLS - 6 + ln;
  const bool xok = (x >= 0) && (x < WI);

  float rring[7];
  h2 wring[7];
  float Hr[7], H0[7], H1[7];
  float Qrr[7], Qrt0[7], Qtt0[7], Qrt1[7], Qtt1[7];
  const h2 hz = {(__fp16)0.f, (__fp16)0.f};
#pragma unroll
  for (int k = 0; k < 7; ++k) {
    rring[k]=0.f; wring[k]=hz;
    Hr[k]=0.f; H0[k]=0.f; H1[k]=0.f;
    Qrr[k]=0.f; Qrt0[k]=0.f; Qtt0[k]=0.f; Qrt1[k]=0.f; Qtt1[k]=0.f;
  }
  float Sr=0.f, S0=0.f, S1=0.f;
  float Vrr=0.f, Vrt0=0.f, Vtt0=0.f, Vrt1=0.f, Vtt1=0.f;
  float cr_p=0.f, c0_p=0.f, c1_p=0.f;   // centered values for row y-4 (prev iter)
  float acc_s=0.f, acc_c=0.f;

  for (int ib = 0; ib < PROWS; ib += 7) {
#pragma unroll
    for (int j = 0; j < 7; ++j) {
      const int y = R0 - 6 + ib + j;
      // raw warped mask for row yo = y-7: capture before overwriting slot j
      const int mb = __builtin_bit_cast(int, wring[j]);

      // ---- static-address inputs at (x,y) ----
      float r = 0.f;
      h2 wp = hz;
      if (xok && y >= 0 && y < HI) {
        const int gidx = y*WI + x;
        r  = ref[gidx];
        wp = __builtin_bit_cast(h2, wmap[gidx]);
      }
      rring[j] = r;
      wring[j] = wp;

      // ---- 4 packed horizontal 7-sums (20 bpermutes total) ----
      h2 A = hsum7p(__builtin_amdgcn_cvt_pkrtz(r, cr_p*cr_p), ln);
      h2 B = hsum7p(wp, ln);
      h2 C = hsum7p(__builtin_amdgcn_cvt_pkrtz(cr_p*c0_p, c0_p*c0_p), ln);
      h2 D = hsum7p(__builtin_amdgcn_cvt_pkrtz(cr_p*c1_p, c1_p*c1_p), ln);
      float hr   = (float)A.x, prr  = (float)A.y;
      float h0   = (float)B.x, h1   = (float)B.y;
      float hrt0 = (float)C.x, htt0 = (float)C.y;
      float hrt1 = (float)D.x, htt1 = (float)D.y;

      // ---- raw vertical box sums; box complete at yc = y-3 ----
      Sr += hr; S0 += h0; S1 += h1;
      const float Br = Sr, B0 = S0, B1 = S1;
      Sr -= Hr[(j+1)%7]; S0 -= H0[(j+1)%7]; S1 -= H1[(j+1)%7];
      Hr[j] = hr; H0[j] = h0; H1[j] = h1;

      // ---- new centered values for row yc = y-3 (consumed NEXT iteration) ----
      const int yc = y - 3;
      float crn = 0.f, c0n = 0.f, c1n = 0.f;
      if (xok && yc >= 0 && yc < HI) {
        h2 wc = wring[(j+4)%7];
        crn = rring[(j+4)%7] - Br*(1.f/49.f);
        c0n = (float)wc.x - B0*(1.f/49.f);
        c1n = (float)wc.y - B1*(1.f/49.f);
      }

      // ---- product vertical sums: this iteration adds product row y-4 ----
      Vrr += prr; Vrt0 += hrt0; Vtt0 += htt0; Vrt1 += hrt1; Vtt1 += htt1;

      // window complete for output row yo = y-7
      const int yo = y - 7;
      if (yo >= R0 && yo < R0 + SROWS && yo < HI && ln >= 6 && ln <= 57 && x < WI) {
        const float inv49 = 1.f/49.f;
        float vr = Vrr*inv49;
        if (mb & 0xffff) {
          float zm = (Vrt0*inv49) * __builtin_amdgcn_rsqf(vr*(Vtt0*inv49) + EPSF);
          acc_s += zm; acc_c += 1.f;
        }
        if (((unsigned)mb >> 16) != 0u) {
          float zm = (Vrt1*inv49) * __builtin_amdgcn_rsqf(vr*(Vtt1*inv49) + EPSF);
          acc_s += zm; acc_c += 1.f;
        }
      }

      Vrr -= Qrr[(j+5)%7]; Vrt0 -= Qrt0[(j+5)%7]; Vtt0 -= Qtt0[(j+5)%7];
      Vrt1 -= Qrt1[(j+5)%7]; Vtt1 -= Qtt1[(j+5)%7];
      Qrr[(j+4)%7] = prr; Qrt0[(j+4)%7] = hrt0; Qtt0[(j+4)%7] = htt0;
      Qrt1[(j+4)%7] = hrt1; Qtt1[(j+4)%7] = htt1;

      cr_p = crn; c0_p = c0n; c1_p = c1n;
    }
  }

  // ---- wave reduce, one partial pair per wave ----
#pragma unroll
  for (int off = 32; off > 0; off >>= 1) {
    acc_s += __shfl_down(acc_s, off, 64);
    acc_c += __shfl_down(acc_c, off, 64);
  }
  if (ln == 0) { partials[2*wid] = acc_s; partials[2*wid+1] = acc_c; }
}

// ============ fallback: fused kernel (used if workspace too small) ======
__global__ __launch_bounds__(256) void k_stream(const float* __restrict__ depth,
                                                const float* __restrict__ ref,
                                                const float* __restrict__ tgts,
                                                const float* __restrict__ mats,
                                                float* __restrict__ partials) {
  const int wid = blockIdx.x*4 + (threadIdx.x >> 6);
  if (wid >= NWAVES) return;
  const int ln = threadIdx.x & 63;
  const int g = wid % NG, st = wid / NG;
  const int R0 = st * SROWS;
  const int x = g*GCOLS - 6 + ln;
  const bool xok = (x >= 0) && (x < WI);

  const float f = mats[24];
  float M0[12], M1[12];
#pragma unroll
  for (int i = 0; i < 12; ++i) { M0[i] = mats[i]; M1[i] = mats[12+i]; }

  const float fx = (float)x;
  const float finv = 1.f/f;
  const float pxc = (fx - 959.5f)*finv;
  const float LA0 = M0[0]*fx + M0[2];
  const float LA1 = M0[3]*fx + M0[5];
  const float LA2 = M0[6]*fx + M0[8];
  const float LB0 = M1[0]*fx + M1[2];
  const float LB1 = M1[3]*fx + M1[5];
  const float LB2 = M1[6]*fx + M1[8];

  float dring[7], rring[7];
  h2 wring[7];
  float Hr[7], H0[7], H1[7];
  float Qrr[7], Qrt0[7], Qtt0[7], Qrt1[7], Qtt1[7];
  const h2 hz = {(__fp16)0.f, (__fp16)0.f};
#pragma unroll
  for (int k = 0; k < 7; ++k) {
    dring[k]=0.f; rring[k]=0.f; wring[k]=hz;
    Hr[k]=0.f; H0[k]=0.f; H1[k]=0.f;
    Qrr[k]=0.f; Qrt0[k]=0.f; Qtt0[k]=0.f; Qrt1[k]=0.f; Qtt1[k]=0.f;
  }
  float Sr=0.f, S0=0.f, S1=0.f;
  float Vrr=0.f, Vrt0=0.f, Vtt0=0.f, Vrt1=0.f, Vtt1=0.f;
  float cr_p=0.f, c0_p=0.f, c1_p=0.f;
  float acc_s=0.f, acc_c=0.f;

  dring[6] = loadI(depth, x, R0-7);
  dring[0] = loadI(depth, x, R0-6);

  for (int ib = 0; ib < PROWS; ib += 7) {
#pragma unroll
    for (int j = 0; j < 7; ++j) {
      const int y = R0 - 6 + ib + j;
      const int mb = __builtin_bit_cast(int, wring[j]);

      dring[(j+1)%7] = loadI(depth, x, y+1);

      float r = 0.f, w0 = 0.f, w1 = 0.f;
      if (xok && y >= 0 && y < HI) {
        const int gidx = y*WI + x;
        r = ref[gidx];
        float d  = dring[j];
        float dm = (x > 0)    ? depth[gidx-1] : 0.f;
        float dp = (x < WI-1) ? depth[gidx+1] : 0.f;
        float du = 0.5f*(dp - dm);
        float dv = 0.5f*(dring[(j+1)%7] - dring[(j+6)%7]);
        const float fy = (float)y;
        float nx = f*du, ny = f*dv;
        float nz = (960.f - fx)*du + (720.f - fy)*dv - d;
        float nn = sqrtf(nx*nx + ny*ny + nz*nz) + EPSF;
        float wsc = __builtin_amdgcn_rcpf(nn*(d + EPSF));
        float pyc = (fy - 719.5f)*finv;
        float sv = (nx*pxc + ny*pyc + nz)*wsc;
        {
          float a0 = fmaf(M0[9],  sv, fmaf(M0[1], fy, LA0));
          float a1 = fmaf(M0[10], sv, fmaf(M0[4], fy, LA1));
          float a2 = fmaf(M0[11], sv, fmaf(M0[7], fy, LA2));
          float iz = __builtin_amdgcn_rcpf(a2 + EPSF);
          w0 = bilerp(tgts, a0*iz, a1*iz);
        }
        {
          float a0 = fmaf(M1[9],  sv, fmaf(M1[1], fy, LB0));
          float a1 = fmaf(M1[10], sv, fmaf(M1[4], fy, LB1));
          float a2 = fmaf(M1[11], sv, fmaf(M1[7], fy, LB2));
          float iz = __builtin_amdgcn_rcpf(a2 + EPSF);
          w1 = bilerp(tgts + NPIX, a0*iz, a1*iz);
        }
      }
      rring[j] = r;
      h2 wp = __builtin_amdgcn_cvt_pkrtz(w0, w1);
      wring[j] = wp;

      h2 A = hsum7p(__builtin_amdgcn_cvt_pkrtz(r, cr_p*cr_p), ln);
      h2 B = hsum7p(wp, ln);
      h2 C = hsum7p(__builtin_amdgcn_cvt_pkrtz(cr_p*c0_p, c0_p*c0_p), ln);
      h2 D = hsum7p(__builtin_amdgcn_cvt_pkrtz(cr_p*c1_p, c1_p*c1_p), ln);
      float hr   = (float)A.x, prr  = (float)A.y;
      float h0   = (float)B.x, h1   = (float)B.y;
      float hrt0 = (float)C.x, htt0 = (float)C.y;
      float hrt1 = (float)D.x, htt1 = (float)D.y;

      Sr += hr; S0 += h0; S1 += h1;
      const float Br = Sr, B0 = S0, B1 = S1;
      Sr -= Hr[(j+1)%7]; S0 -= H0[(j+1)%7]; S1 -= H1[(j+1)%7];
      Hr[j] = hr; H0[j] = h0; H1[j] = h1;

      const int yc = y - 3;
      float crn = 0.f, c0n = 0.f, c1n = 0.f;
      if (xok && yc >= 0 && yc < HI) {
        h2 wc = wring[(j+4)%7];
        crn = rring[(j+4)%7] - Br*(1.f/49.f);
        c0n = (float)wc.x - B0*(1.f/49.f);
        c1n = (float)wc.y - B1*(1.f/49.f);
      }

      Vrr += prr; Vrt0 += hrt0; Vtt0 += htt0; Vrt1 += hrt1; Vtt1 += htt1;

      const int yo = y - 7;
      if (yo >= R0 && yo < R0 + SROWS && yo < HI && ln >= 6 && ln <= 57 && x < WI) {
        const float inv49 = 1.f/49.f;
        float vr = Vrr*inv49;
        if (mb & 0xffff) {
          float zm = (Vrt0*inv49) * __builtin_amdgcn_rsqf(vr*(Vtt0*inv49) + EPSF);
          acc_s += zm; acc_c += 1.f;
        }
        if (((unsigned)mb >> 16) != 0u) {
          float zm = (Vrt1*inv49) * __builtin_amdgcn_rsqf(vr*(Vtt1*inv49) + EPSF);
          acc_s += zm; acc_c += 1.f;
        }
      }

      Vrr -= Qrr[(j+5)%7]; Vrt0 -= Qrt0[(j+5)%7]; Vtt0 -= Qtt0[(j+5)%7];
      Vrt1 -= Qrt1[(j+5)%7]; Vtt1 -= Qtt1[(j+5)%7];
      Qrr[(j+4)%7] = prr; Qrt0[(j+4)%7] = hrt0; Qtt0[(j+4)%7] = htt0;
      Qrt1[(j+4)%7] = hrt1; Qtt1[(j+4)%7] = htt1;

      cr_p = crn; c0_p = c0n; c1_p = c1n;
    }
  }

#pragma unroll
  for (int off = 32; off > 0; off >>= 1) {
    acc_s += __shfl_down(acc_s, off, 64);
    acc_c += __shfl_down(acc_c, off, 64);
  }
  if (ln == 0) { partials[2*wid] = acc_s; partials[2*wid+1] = acc_c; }
}

__global__ __launch_bounds__(256) void k_final(const float* __restrict__ partials, int nb,
                                               float* __restrict__ out) {
  float s = 0.f, c = 0.f;
  for (int i = threadIdx.x; i < nb; i += 256) {
    s += partials[2*i];
    c += partials[2*i+1];
  }
#pragma unroll
  for (int off = 32; off > 0; off >>= 1) {
    s += __shfl_down(s, off, 64);
    c += __shfl_down(c, off, 64);
  }
  __shared__ float red[8];
  int tid = threadIdx.x;
  if ((tid & 63) == 0) { red[(tid>>6)*2] = s; red[(tid>>6)*2+1] = c; }
  __syncthreads();
  if (tid == 0) {
    float S = red[0]+red[2]+red[4]+red[6];
    float C = red[1]+red[3]+red[5]+red[7];
    float mean = S / fmaxf(C, 1.f);
    out[0] = (C > 0.f) ? 0.5f*(1.f - mean) : 0.f;
  }
}

extern "C" void kernel_launch(void* const* d_in, const int* in_sizes, int n_in,
                              void* d_out, int out_size, void* d_ws, size_t ws_size,
                              hipStream_t stream) {
  const float* focal  = (const float*)d_in[0];
  const float* aa     = (const float*)d_in[1];
  const float* cen    = (const float*)d_in[2];
  const float* ref    = (const float*)d_in[3];
  const float* depth  = (const float*)d_in[4];
  const float* tgts   = (const float*)d_in[5];
  float* out = (float*)d_out;

  float* wsf      = (float*)d_ws;
  float* mats     = wsf;                       // 32 floats
  float* partials = wsf + 32;                  // 2*NWAVES floats
  unsigned* wmap  = (unsigned*)(wsf + 32 + 2*NWAVES);   // NPIX u32

  const size_t need = (size_t)(32 + 2*NWAVES)*4 + (size_t)NPIX*4;

  k_pre<<<1, 64, 0, stream>>>(focal, aa, cen, mats);
  if (ws_size >= need) {
    k_warp<<<NPIX/256, 256, 0, stream>>>(depth, tgts, mats, wmap);
    k_win<<<(NWAVES + 3)/4, 256, 0, stream>>>(ref, wmap, partials);
  } else {
    k_stream<<<(NWAVES + 3)/4, 256, 0, stream>>>(depth, ref, tgts, mats, partials);
  }
  k_final<<<1, 256, 0, stream>>>(partials, NWAVES, out);
}